// Round 1
// baseline (3080.158 us; speedup 1.0000x reference)
//
#include <hip/hip_runtime.h>
#include <math.h>

#define FH 160
#define FW 160
#define NPOS (FH*FW)        // 25600
#define NANCH (NPOS*9)      // 230400
#define IMG 2560.0f
#define STRIDE 16.0f

// ---------------------------------------------------------------------------
// conv1: 3x3, 512->512, SAME pad, +bias, ReLU.  Implicit GEMM:
// M=25600 positions, N=512 oc, K=9*512.  BM=64, BN=64, BK=32, 256 thr, 4x4/thr.
// LDS stride 66 (odd*2): conflict-free writes, b64-aligned frag reads.
// ---------------------------------------------------------------------------
__global__ __launch_bounds__(256) void conv1_kernel(
    const float* __restrict__ f, const float* __restrict__ w,
    const float* __restrict__ bias, float* __restrict__ xout)
{
    __shared__ float As[32][66];
    __shared__ float Bs[32][66];
    const int tid = threadIdx.x;
    const int nt = blockIdx.x;          // 0..7   (oc tile)
    const int mt = blockIdx.y;          // 0..399 (pos tile)
    const int p0 = mt*64, oc0 = nt*64;
    const int tm = tid & 15, tn = tid >> 4;
    const int kA = tid & 31, mA = tid >> 5;   // A loader: ic-in-chunk, row base
    const int nB = tid & 63, kB = tid >> 6;   // B loader

    int yv[8], xv[8];
#pragma unroll
    for (int it = 0; it < 8; ++it) {
        int p = p0 + mA + it*8;
        yv[it] = p / FW;
        xv[it] = p - yv[it]*FW;
    }

    float acc[4][4] = {};

    for (int tap = 0; tap < 9; ++tap) {
        const int ky = tap/3 - 1, kx = tap%3 - 1;
        for (int icb = 0; icb < 512; icb += 32) {
#pragma unroll
            for (int it = 0; it < 8; ++it) {
                int yy = yv[it] + ky, xx = xv[it] + kx;
                float v = 0.f;
                if ((unsigned)yy < (unsigned)FH && (unsigned)xx < (unsigned)FW)
                    v = f[(((yy*FW)+xx)<<9) + icb + kA];
                As[kA][mA + it*8] = v;
            }
            const float* wp = w + ((size_t)(tap*512 + icb + kB))*512 + oc0 + nB;
#pragma unroll
            for (int it = 0; it < 8; ++it)
                Bs[kB + it*4][nB] = wp[(size_t)it*4*512];
            __syncthreads();
#pragma unroll 8
            for (int kk = 0; kk < 32; ++kk) {
                float a0 = As[kk][4*tm+0], a1 = As[kk][4*tm+1],
                      a2 = As[kk][4*tm+2], a3 = As[kk][4*tm+3];
                float b0 = Bs[kk][4*tn+0], b1 = Bs[kk][4*tn+1],
                      b2 = Bs[kk][4*tn+2], b3 = Bs[kk][4*tn+3];
                acc[0][0] += a0*b0; acc[0][1] += a0*b1; acc[0][2] += a0*b2; acc[0][3] += a0*b3;
                acc[1][0] += a1*b0; acc[1][1] += a1*b1; acc[1][2] += a1*b2; acc[1][3] += a1*b3;
                acc[2][0] += a2*b0; acc[2][1] += a2*b1; acc[2][2] += a2*b2; acc[2][3] += a2*b3;
                acc[3][0] += a3*b0; acc[3][1] += a3*b1; acc[3][2] += a3*b2; acc[3][3] += a3*b3;
            }
            __syncthreads();
        }
    }
#pragma unroll
    for (int i = 0; i < 4; ++i) {
        int p = p0 + 4*tm + i;
        float4 o;
        float* op = &o.x;
#pragma unroll
        for (int j = 0; j < 4; ++j) {
            float v = acc[i][j] + bias[oc0 + 4*tn + j];
            op[j] = v > 0.f ? v : 0.f;
        }
        *(float4*)(xout + (size_t)p*512 + oc0 + 4*tn) = o;
    }
}

// ---------------------------------------------------------------------------
// Transpose the 99 useful head weight columns (HWIO, strided) into wT[99][512]
// so the heads kernel can read contiguous float4.
// u<36: reg channel (u/4)*8 + u%4 ; 36..44: cls ; 45..98: lm
// ---------------------------------------------------------------------------
__global__ __launch_bounds__(256) void wprep_kernel(
    const float* __restrict__ regw, const float* __restrict__ clsw,
    const float* __restrict__ lmw, float* __restrict__ wT)
{
    int i = blockIdx.x*256 + threadIdx.x;
    if (i >= 99*512) return;
    int u = i >> 9, c = i & 511;
    float v;
    if (u < 36)      v = regw[c*72 + (u>>2)*8 + (u&3)];
    else if (u < 45) v = clsw[c*9 + (u-36)];
    else             v = lmw[c*54 + (u-45)];
    wT[i] = v;
}

// ---------------------------------------------------------------------------
// heads: 1x1 convs. Block = 16 positions, 256 threads.
// Thread mapping oi = u*16 + ps  (u slow => weight reads broadcast per 16 lanes)
// xs padded to stride 516 floats to break the 512-stride bank collision.
// ---------------------------------------------------------------------------
__global__ __launch_bounds__(256) void heads_kernel(
    const float* __restrict__ x, const float* __restrict__ wT,
    const float* __restrict__ regb, const float* __restrict__ clsb,
    const float* __restrict__ lmb,
    float* __restrict__ lm_out, float* __restrict__ deltas,
    float* __restrict__ s_arr)
{
    __shared__ float xs[16*516];
    const int p0 = blockIdx.x * 16;
    const float4* src = (const float4*)(x + (size_t)p0*512);
    for (int i = threadIdx.x; i < 16*128; i += 256) {
        int row = i >> 7, c4 = i & 127;
        *(float4*)(xs + row*516 + c4*4) = src[row*128 + c4];
    }
    __syncthreads();
    for (int oi = threadIdx.x; oi < 99*16; oi += 256) {
        int ps = oi & 15, u = oi >> 4;
        const float4* wv = (const float4*)(wT + (u << 9));
        const float4* xv = (const float4*)(xs + ps*516);
        float acc = 0.f;
#pragma unroll 4
        for (int c = 0; c < 128; ++c) {
            float4 a = xv[c], b = wv[c];
            acc += a.x*b.x + a.y*b.y + a.z*b.z + a.w*b.w;
        }
        int p = p0 + ps;
        if (u < 36) {
            int aidx = u >> 2, r = u & 3;
            deltas[(size_t)(p*9 + aidx)*4 + r] = acc + regb[aidx*8 + r];
        } else if (u < 45) {
            float z = acc + clsb[u-36];
            s_arr[p*9 + (u-36)] = 1.f/(1.f + expf(-z));
        } else {
            lm_out[(size_t)p*54 + (u-45)] = acc + lmb[u-45];
        }
    }
}

// ---------------------------------------------------------------------------
// decode: anchors -> d_out, boxes -> ws, mask invalid scores to -1, init slot.
// ---------------------------------------------------------------------------
__global__ __launch_bounds__(256) void decode_kernel(
    const float* __restrict__ deltas, float* __restrict__ s_arr,
    float* __restrict__ boxes, float* __restrict__ anch_out,
    unsigned long long* __restrict__ slot)
{
    int n = blockIdx.x*256 + threadIdx.x;
    if (n == 0) *slot = 0ull;
    if (n >= NANCH) return;
    int p = n / 9, a = n - 9*p;
    int y = p / FW, x = p - FW*y;
    float cx = (x + 0.5f)*STRIDE, cy = (y + 0.5f)*STRIDE;
    const float rr[3] = {0.5f, 1.f, 2.f};
    const float ss[3] = {8.f, 16.f, 32.f};
    float r = rr[a/3], sv = ss[a - (a/3)*3];
    float h  = sqrtf(sv*sv/r)*STRIDE;
    float wv = h * r;                       // x_stride/y_stride == 1
    float x1a = cx - wv*0.5f, y1a = cy - h*0.5f;
    float x2a = cx + wv*0.5f, y2a = cy + h*0.5f;
    float4 av = {x1a, y1a, x2a, y2a};
    *(float4*)(anch_out + (size_t)4*n) = av;
    bool valid = (x1a >= 0.f) && (y1a >= 0.f) && (x2a <= IMG) && (y2a <= IMG);

    float4 d = *(const float4*)(deltas + (size_t)4*n);
    float px = cx + wv*d.x, py = cy + h*d.y;
    float pw = wv*expf(d.z), ph = h*expf(d.w);
    float bx1 = px - pw*0.5f, by1 = py - ph*0.5f;
    float4 b;
    b.x = fminf(fmaxf(bx1, 0.f), IMG);
    b.y = fminf(fmaxf(by1, 0.f), IMG);
    b.z = fminf(fmaxf(bx1 + pw, 0.f), IMG);
    b.w = fminf(fmaxf(by1 + ph, 0.f), IMG);
    *(float4*)(boxes + (size_t)4*n) = b;
    if (!valid) s_arr[n] = -1.f;
}

// ---------------------------------------------------------------------------
// NMS iteration: suppress vs previous winner (k>0), then grid argmax via
// packed (sortable score, ~index) u64: wave-reduce then 1 atomicMax per wave.
// Tie semantics match jnp.argmax (max score, then lowest index).
// ---------------------------------------------------------------------------
__global__ __launch_bounds__(256) void nms_iter_kernel(
    const float* __restrict__ boxes, float* __restrict__ s_arr,
    const float* __restrict__ wbox, unsigned long long* __restrict__ slot,
    int k)
{
    int n = blockIdx.x*256 + threadIdx.x;   // grid covers exactly NANCH
    float s = s_arr[n];
    if (k > 0) {
        float wx1 = wbox[0], wy1 = wbox[1], wx2 = wbox[2], wy2 = wbox[3];
        float4 b = *(const float4*)(boxes + (size_t)4*n);
        float ix = fminf(wx2, b.z) - fmaxf(wx1, b.x);
        float iy = fminf(wy2, b.w) - fmaxf(wy1, b.y);
        float inter = fmaxf(ix, 0.f)*fmaxf(iy, 0.f);
        float a1 = (wx2-wx1)*(wy2-wy1);
        float a2 = (b.z-b.x)*(b.w-b.y);
        float iou = inter/(a1 + a2 - inter + 1e-9f);
        if (iou > 0.5f) { s = -1.f; s_arr[n] = -1.f; }
    }
    unsigned int bu = __float_as_uint(s);
    unsigned int key = (bu & 0x80000000u) ? ~bu : (bu | 0x80000000u);
    unsigned long long packed =
        ((unsigned long long)key << 32) | (unsigned int)~(unsigned int)n;
#pragma unroll
    for (int off = 32; off > 0; off >>= 1) {
        unsigned long long o = __shfl_xor(packed, off, 64);
        packed = packed > o ? packed : o;
    }
    if ((threadIdx.x & 63) == 0) atomicMax(slot, packed);
}

__global__ void nms_pick_kernel(
    const float* __restrict__ boxes, float* __restrict__ wbox,
    unsigned long long* __restrict__ slot, float* __restrict__ rois, int k)
{
    if (threadIdx.x != 0) return;
    unsigned long long v = *slot;
    unsigned int n = ~(unsigned int)(v & 0xFFFFFFFFull);
    float4 b = *(const float4*)(boxes + (size_t)4*n);
    wbox[0] = b.x; wbox[1] = b.y; wbox[2] = b.z; wbox[3] = b.w;
    rois[k*4+0] = b.x; rois[k*4+1] = b.y; rois[k*4+2] = b.z; rois[k*4+3] = b.w;
    *slot = 0ull;   // reset for next iteration's argmax
}

// ---------------------------------------------------------------------------
extern "C" void kernel_launch(void* const* d_in, const int* in_sizes, int n_in,
                              void* d_out, int out_size, void* d_ws, size_t ws_size,
                              hipStream_t stream)
{
    const float* f    = (const float*)d_in[0];
    // d_in[1] = image, only shape (2560x2560) is consumed -> hardcoded
    const float* c1w  = (const float*)d_in[2];
    const float* c1b  = (const float*)d_in[3];
    const float* regw = (const float*)d_in[4];
    const float* regb = (const float*)d_in[5];
    const float* clsw = (const float*)d_in[6];
    const float* clsb = (const float*)d_in[7];
    const float* lmw  = (const float*)d_in[8];
    const float* lmb  = (const float*)d_in[9];

    float* out      = (float*)d_out;
    float* rois     = out;                              // 24
    float* lm_out   = out + 24;                         // 1,382,400
    float* anch_out = out + 24 + (size_t)NPOS*54;       // 921,600

    // workspace layout (bytes)
    char* ws = (char*)d_ws;
    unsigned long long* slot = (unsigned long long*)ws;        // 8 B
    float* wbox   = (float*)(ws + 16);                         // 16 B
    float* wT     = (float*)(ws + 256);                        // 99*512*4 = 202,752
    float* boxes  = (float*)(ws + 256 + 202752);               // 3,686,400
    float* deltas = (float*)(ws + 256 + 202752 + 3686400);     // 3,686,400
    float* s_arr  = (float*)(ws + 256 + 202752 + 2*3686400);   // 921,600
    float* x      = (float*)(ws + 256 + 202752 + 2*3686400 + 921600); // 52,428,800

    wprep_kernel<<<(99*512 + 255)/256, 256, 0, stream>>>(regw, clsw, lmw, wT);
    conv1_kernel<<<dim3(8, 400), 256, 0, stream>>>(f, c1w, c1b, x);
    heads_kernel<<<NPOS/16, 256, 0, stream>>>(x, wT, regb, clsb, lmb,
                                              lm_out, deltas, s_arr);
    decode_kernel<<<NANCH/256, 256, 0, stream>>>(deltas, s_arr, boxes,
                                                 anch_out, slot);
    for (int k = 0; k < 6; ++k) {
        nms_iter_kernel<<<NANCH/256, 256, 0, stream>>>(boxes, s_arr, wbox, slot, k);
        nms_pick_kernel<<<1, 64, 0, stream>>>(boxes, wbox, slot, rois, k);
    }
}

// Round 2
// 1044.687 us; speedup vs baseline: 2.9484x; 2.9484x over previous
//
#include <hip/hip_runtime.h>
#include <math.h>

#define FH 160
#define FW 160
#define NPOS (FH*FW)        // 25600
#define NANCH (NPOS*9)      // 230400
#define IMG 2560.0f
#define STRIDE 16.0f

typedef __attribute__((ext_vector_type(8))) short short8;
typedef __attribute__((ext_vector_type(4))) float f32x4;

__device__ __forceinline__ unsigned short bf16_rne(float v) {
    unsigned u = __float_as_uint(v);
    return (unsigned short)((u + 0x7FFFu + ((u >> 16) & 1u)) >> 16);
}
__device__ __forceinline__ float bf16_to_f(unsigned short b) {
    return __uint_as_float(((unsigned)b) << 16);
}

__device__ __forceinline__ void g2l16(void* lds, const void* g) {
    __builtin_amdgcn_global_load_lds(
        (const __attribute__((address_space(1))) void*)g,
        (__attribute__((address_space(3))) void*)lds, 16, 0, 0);
}

// ---------------------------------------------------------------------------
// fprep: pad features to [162][162][512] and split fp32 -> bf16 hi/lo.
// ---------------------------------------------------------------------------
__global__ __launch_bounds__(256) void fprep_kernel(
    const float* __restrict__ f, unsigned short* __restrict__ fph,
    unsigned short* __restrict__ fpl)
{
    int idx = blockIdx.x*256 + threadIdx.x;   // 162*162*128 threads, 4 ch each
    int c4 = (idx & 127) << 2;
    int rest = idx >> 7;
    int x = rest % 162, y = rest / 162;
    float4 v = make_float4(0.f, 0.f, 0.f, 0.f);
    if (y > 0 && y < 161 && x > 0 && x < 161)
        v = *(const float4*)(f + ((size_t)((y-1)*FW + (x-1)) << 9) + c4);
    ushort4 h, l;
    h.x = bf16_rne(v.x); l.x = bf16_rne(v.x - bf16_to_f(h.x));
    h.y = bf16_rne(v.y); l.y = bf16_rne(v.y - bf16_to_f(h.y));
    h.z = bf16_rne(v.z); l.z = bf16_rne(v.z - bf16_to_f(h.z));
    h.w = bf16_rne(v.w); l.w = bf16_rne(v.w - bf16_to_f(h.w));
    size_t o = ((size_t)(y*162 + x) << 9) + c4;
    *(ushort4*)(fph + o) = h;
    *(ushort4*)(fpl + o) = l;
}

// ---------------------------------------------------------------------------
// wprep2: transpose conv1 weights [4608 k][512 oc] -> [512 oc][4608 k],
// split to bf16 hi/lo. 32x32 LDS tile transpose.
// ---------------------------------------------------------------------------
__global__ __launch_bounds__(256) void wprep2_kernel(
    const float* __restrict__ w, unsigned short* __restrict__ wth,
    unsigned short* __restrict__ wtl)
{
    __shared__ float tile[32][33];
    int k0 = blockIdx.x*32, oc0 = blockIdx.y*32;
    int t = threadIdx.x;
    int c = t & 31, r8 = t >> 5;
#pragma unroll
    for (int i = 0; i < 4; ++i) {
        int r = r8 + i*8;
        tile[c][r] = w[(size_t)(k0 + r)*512 + oc0 + c];
    }
    __syncthreads();
#pragma unroll
    for (int i = 0; i < 4; ++i) {
        int orow = r8 + i*8, kcol = c;
        float v = tile[orow][kcol];
        unsigned short hi = bf16_rne(v);
        unsigned short lo = bf16_rne(v - bf16_to_f(hi));
        size_t o = (size_t)(oc0 + orow)*4608 + k0 + kcol;
        wth[o] = hi; wtl[o] = lo;
    }
}

// ---------------------------------------------------------------------------
// conv1 via MFMA: implicit GEMM M=25600, N=512, K=9*512, 3-term hi/lo bf16.
// Block 256 thr (4 waves 2x2), tile BM=128(4y x 32x) BN=128 BK=32.
// m97 structure: global_load_lds(16B) staging, 2-barrier K-loop,
// 16x16x32 bf16 MFMA (m89-verified layouts). LDS rows [128][32] bf16 = 64B.
// ---------------------------------------------------------------------------
__global__ __launch_bounds__(256) void conv1_mfma_kernel(
    const unsigned short* __restrict__ fph, const unsigned short* __restrict__ fpl,
    const unsigned short* __restrict__ wth, const unsigned short* __restrict__ wtl,
    const float* __restrict__ bias, float* __restrict__ xout)
{
    __shared__ unsigned short As_h[128*32], As_l[128*32];
    __shared__ unsigned short Bs_h[128*32], Bs_l[128*32];
    const int tid  = threadIdx.x;
    const int lane = tid & 63;
    const int wi   = (tid >> 7) & 1;
    const int wj   = (tid >> 6) & 1;
    const int nt = blockIdx.x, mt = blockIdx.y;
    const int ty = mt / 5, tx = mt - ty*5;
    const int y0 = ty*4, x0 = tx*32;
    const int oc0 = nt*128;

    // staging mapping: thread -> (row = tid>>2, koff = (tid&3)*8 elements)
    const int srow = tid >> 2;
    const int koff = (tid & 3) << 3;
    const int ry0 = srow >> 5,        rx0 = srow & 31;
    const int ry1 = (srow + 64) >> 5, rx1 = (srow + 64) & 31;

    unsigned short* dA0h = As_h + srow*32 + koff;
    unsigned short* dA1h = As_h + (srow+64)*32 + koff;
    unsigned short* dA0l = As_l + srow*32 + koff;
    unsigned short* dA1l = As_l + (srow+64)*32 + koff;
    unsigned short* dB0h = Bs_h + srow*32 + koff;
    unsigned short* dB1h = Bs_h + (srow+64)*32 + koff;
    unsigned short* dB0l = Bs_l + srow*32 + koff;
    unsigned short* dB1l = Bs_l + (srow+64)*32 + koff;

    const size_t bofs0 = (size_t)(oc0 + srow)*4608 + koff;
    const size_t bofs1 = (size_t)(oc0 + srow + 64)*4608 + koff;

    const int quad = lane >> 4, fr = lane & 15;
    int aoff[4], boff[4];
#pragma unroll
    for (int b = 0; b < 4; ++b) {
        aoff[b] = (wi*64 + b*16 + fr)*32 + quad*8;
        boff[b] = (wj*64 + b*16 + fr)*32 + quad*8;
    }

    f32x4 acc[4][4] = {};

    for (int tap = 0; tap < 9; ++tap) {
        const int ky = tap/3, kx = tap - ky*3;
        const size_t ga0 = ((size_t)((y0+ry0+ky)*162 + (x0+rx0+kx)) << 9) + koff;
        const size_t ga1 = ((size_t)((y0+ry1+ky)*162 + (x0+rx1+kx)) << 9) + koff;
        const size_t gb0 = bofs0 + tap*512;
        const size_t gb1 = bofs1 + tap*512;
        for (int icb = 0; icb < 512; icb += 32) {
            g2l16(dA0h, fph + ga0 + icb);
            g2l16(dA1h, fph + ga1 + icb);
            g2l16(dA0l, fpl + ga0 + icb);
            g2l16(dA1l, fpl + ga1 + icb);
            g2l16(dB0h, wth + gb0 + icb);
            g2l16(dB1h, wth + gb1 + icb);
            g2l16(dB0l, wtl + gb0 + icb);
            g2l16(dB1l, wtl + gb1 + icb);
            __syncthreads();
            short8 ah[4], al[4], bh[4], bl[4];
#pragma unroll
            for (int b = 0; b < 4; ++b) {
                ah[b] = *(const short8*)(As_h + aoff[b]);
                al[b] = *(const short8*)(As_l + aoff[b]);
                bh[b] = *(const short8*)(Bs_h + boff[b]);
                bl[b] = *(const short8*)(Bs_l + boff[b]);
            }
#pragma unroll
            for (int i = 0; i < 4; ++i)
#pragma unroll
                for (int j = 0; j < 4; ++j) {
                    acc[i][j] = __builtin_amdgcn_mfma_f32_16x16x32_bf16(ah[i], bh[j], acc[i][j], 0, 0, 0);
                    acc[i][j] = __builtin_amdgcn_mfma_f32_16x16x32_bf16(ah[i], bl[j], acc[i][j], 0, 0, 0);
                    acc[i][j] = __builtin_amdgcn_mfma_f32_16x16x32_bf16(al[i], bh[j], acc[i][j], 0, 0, 0);
                }
            __syncthreads();
        }
    }

    // epilogue: C/D layout col=lane&15 (oc), row=(lane>>4)*4+reg (position)
#pragma unroll
    for (int i = 0; i < 4; ++i) {
        int prow = wi*64 + i*16 + quad*4;
#pragma unroll
        for (int r = 0; r < 4; ++r) {
            int pi = prow + r;
            int p = (y0 + (pi >> 5))*FW + x0 + (pi & 31);
#pragma unroll
            for (int j = 0; j < 4; ++j) {
                int col = oc0 + wj*64 + j*16 + fr;
                float v = acc[i][j][r] + bias[col];
                xout[(size_t)p*512 + col] = v > 0.f ? v : 0.f;
            }
        }
    }
}

// ---------------------------------------------------------------------------
// fallback fp32 conv1 (known-good) for small ws_size
// ---------------------------------------------------------------------------
__global__ __launch_bounds__(256) void conv1_kernel(
    const float* __restrict__ f, const float* __restrict__ w,
    const float* __restrict__ bias, float* __restrict__ xout)
{
    __shared__ float As[32][66];
    __shared__ float Bs[32][66];
    const int tid = threadIdx.x;
    const int nt = blockIdx.x;
    const int mt = blockIdx.y;
    const int p0 = mt*64, oc0 = nt*64;
    const int tm = tid & 15, tn = tid >> 4;
    const int kA = tid & 31, mA = tid >> 5;
    const int nB = tid & 63, kB = tid >> 6;

    int yv[8], xv[8];
#pragma unroll
    for (int it = 0; it < 8; ++it) {
        int p = p0 + mA + it*8;
        yv[it] = p / FW;
        xv[it] = p - yv[it]*FW;
    }
    float acc[4][4] = {};
    for (int tap = 0; tap < 9; ++tap) {
        const int ky = tap/3 - 1, kx = tap%3 - 1;
        for (int icb = 0; icb < 512; icb += 32) {
#pragma unroll
            for (int it = 0; it < 8; ++it) {
                int yy = yv[it] + ky, xx = xv[it] + kx;
                float v = 0.f;
                if ((unsigned)yy < (unsigned)FH && (unsigned)xx < (unsigned)FW)
                    v = f[(((yy*FW)+xx)<<9) + icb + kA];
                As[kA][mA + it*8] = v;
            }
            const float* wp = w + ((size_t)(tap*512 + icb + kB))*512 + oc0 + nB;
#pragma unroll
            for (int it = 0; it < 8; ++it)
                Bs[kB + it*4][nB] = wp[(size_t)it*4*512];
            __syncthreads();
#pragma unroll 8
            for (int kk = 0; kk < 32; ++kk) {
                float a0 = As[kk][4*tm+0], a1 = As[kk][4*tm+1],
                      a2 = As[kk][4*tm+2], a3 = As[kk][4*tm+3];
                float b0 = Bs[kk][4*tn+0], b1 = Bs[kk][4*tn+1],
                      b2 = Bs[kk][4*tn+2], b3 = Bs[kk][4*tn+3];
                acc[0][0] += a0*b0; acc[0][1] += a0*b1; acc[0][2] += a0*b2; acc[0][3] += a0*b3;
                acc[1][0] += a1*b0; acc[1][1] += a1*b1; acc[1][2] += a1*b2; acc[1][3] += a1*b3;
                acc[2][0] += a2*b0; acc[2][1] += a2*b1; acc[2][2] += a2*b2; acc[2][3] += a2*b3;
                acc[3][0] += a3*b0; acc[3][1] += a3*b1; acc[3][2] += a3*b2; acc[3][3] += a3*b3;
            }
            __syncthreads();
        }
    }
#pragma unroll
    for (int i = 0; i < 4; ++i) {
        int p = p0 + 4*tm + i;
        float4 o;
        float* op = &o.x;
#pragma unroll
        for (int j = 0; j < 4; ++j) {
            float v = acc[i][j] + bias[oc0 + 4*tn + j];
            op[j] = v > 0.f ? v : 0.f;
        }
        *(float4*)(xout + (size_t)p*512 + oc0 + 4*tn) = o;
    }
}

// ---------------------------------------------------------------------------
__global__ __launch_bounds__(256) void wprep_kernel(
    const float* __restrict__ regw, const float* __restrict__ clsw,
    const float* __restrict__ lmw, float* __restrict__ wT)
{
    int i = blockIdx.x*256 + threadIdx.x;
    if (i >= 99*512) return;
    int u = i >> 9, c = i & 511;
    float v;
    if (u < 36)      v = regw[c*72 + (u>>2)*8 + (u&3)];
    else if (u < 45) v = clsw[c*9 + (u-36)];
    else             v = lmw[c*54 + (u-45)];
    wT[i] = v;
}

__global__ __launch_bounds__(256) void heads_kernel(
    const float* __restrict__ x, const float* __restrict__ wT,
    const float* __restrict__ regb, const float* __restrict__ clsb,
    const float* __restrict__ lmb,
    float* __restrict__ lm_out, float* __restrict__ deltas,
    float* __restrict__ s_arr)
{
    __shared__ float xs[16*516];
    const int p0 = blockIdx.x * 16;
    const float4* src = (const float4*)(x + (size_t)p0*512);
    for (int i = threadIdx.x; i < 16*128; i += 256) {
        int row = i >> 7, c4 = i & 127;
        *(float4*)(xs + row*516 + c4*4) = src[row*128 + c4];
    }
    __syncthreads();
    for (int oi = threadIdx.x; oi < 99*16; oi += 256) {
        int ps = oi & 15, u = oi >> 4;
        const float4* wv = (const float4*)(wT + (u << 9));
        const float4* xv = (const float4*)(xs + ps*516);
        float acc = 0.f;
#pragma unroll 4
        for (int c = 0; c < 128; ++c) {
            float4 a = xv[c], b = wv[c];
            acc += a.x*b.x + a.y*b.y + a.z*b.z + a.w*b.w;
        }
        int p = p0 + ps;
        if (u < 36) {
            int aidx = u >> 2, r = u & 3;
            deltas[(size_t)(p*9 + aidx)*4 + r] = acc + regb[aidx*8 + r];
        } else if (u < 45) {
            float z = acc + clsb[u-36];
            s_arr[p*9 + (u-36)] = 1.f/(1.f + expf(-z));
        } else {
            lm_out[(size_t)p*54 + (u-45)] = acc + lmb[u-45];
        }
    }
}

__global__ __launch_bounds__(256) void decode_kernel(
    const float* __restrict__ deltas, float* __restrict__ s_arr,
    float* __restrict__ boxes, float* __restrict__ anch_out,
    unsigned long long* __restrict__ slot)
{
    int n = blockIdx.x*256 + threadIdx.x;
    if (n == 0) *slot = 0ull;
    if (n >= NANCH) return;
    int p = n / 9, a = n - 9*p;
    int y = p / FW, x = p - FW*y;
    float cx = (x + 0.5f)*STRIDE, cy = (y + 0.5f)*STRIDE;
    const float rr[3] = {0.5f, 1.f, 2.f};
    const float ss[3] = {8.f, 16.f, 32.f};
    float r = rr[a/3], sv = ss[a - (a/3)*3];
    float h  = sqrtf(sv*sv/r)*STRIDE;
    float wv = h * r;
    float x1a = cx - wv*0.5f, y1a = cy - h*0.5f;
    float x2a = cx + wv*0.5f, y2a = cy + h*0.5f;
    float4 av = {x1a, y1a, x2a, y2a};
    *(float4*)(anch_out + (size_t)4*n) = av;
    bool valid = (x1a >= 0.f) && (y1a >= 0.f) && (x2a <= IMG) && (y2a <= IMG);

    float4 d = *(const float4*)(deltas + (size_t)4*n);
    float px = cx + wv*d.x, py = cy + h*d.y;
    float pw = wv*expf(d.z), ph = h*expf(d.w);
    float bx1 = px - pw*0.5f, by1 = py - ph*0.5f;
    float4 b;
    b.x = fminf(fmaxf(bx1, 0.f), IMG);
    b.y = fminf(fmaxf(by1, 0.f), IMG);
    b.z = fminf(fmaxf(bx1 + pw, 0.f), IMG);
    b.w = fminf(fmaxf(by1 + ph, 0.f), IMG);
    *(float4*)(boxes + (size_t)4*n) = b;
    if (!valid) s_arr[n] = -1.f;
}

__global__ __launch_bounds__(256) void nms_iter_kernel(
    const float* __restrict__ boxes, float* __restrict__ s_arr,
    const float* __restrict__ wbox, unsigned long long* __restrict__ slot,
    int k)
{
    int n = blockIdx.x*256 + threadIdx.x;
    float s = s_arr[n];
    if (k > 0) {
        float wx1 = wbox[0], wy1 = wbox[1], wx2 = wbox[2], wy2 = wbox[3];
        float4 b = *(const float4*)(boxes + (size_t)4*n);
        float ix = fminf(wx2, b.z) - fmaxf(wx1, b.x);
        float iy = fminf(wy2, b.w) - fmaxf(wy1, b.y);
        float inter = fmaxf(ix, 0.f)*fmaxf(iy, 0.f);
        float a1 = (wx2-wx1)*(wy2-wy1);
        float a2 = (b.z-b.x)*(b.w-b.y);
        float iou = inter/(a1 + a2 - inter + 1e-9f);
        if (iou > 0.5f) { s = -1.f; s_arr[n] = -1.f; }
    }
    unsigned int bu = __float_as_uint(s);
    unsigned int key = (bu & 0x80000000u) ? ~bu : (bu | 0x80000000u);
    unsigned long long packed =
        ((unsigned long long)key << 32) | (unsigned int)~(unsigned int)n;
#pragma unroll
    for (int off = 32; off > 0; off >>= 1) {
        unsigned long long o = __shfl_xor(packed, off, 64);
        packed = packed > o ? packed : o;
    }
    if ((threadIdx.x & 63) == 0) atomicMax(slot, packed);
}

__global__ void nms_pick_kernel(
    const float* __restrict__ boxes, float* __restrict__ wbox,
    unsigned long long* __restrict__ slot, float* __restrict__ rois, int k)
{
    if (threadIdx.x != 0) return;
    unsigned long long v = *slot;
    unsigned int n = ~(unsigned int)(v & 0xFFFFFFFFull);
    float4 b = *(const float4*)(boxes + (size_t)4*n);
    wbox[0] = b.x; wbox[1] = b.y; wbox[2] = b.z; wbox[3] = b.w;
    rois[k*4+0] = b.x; rois[k*4+1] = b.y; rois[k*4+2] = b.z; rois[k*4+3] = b.w;
    *slot = 0ull;
}

// ---------------------------------------------------------------------------
extern "C" void kernel_launch(void* const* d_in, const int* in_sizes, int n_in,
                              void* d_out, int out_size, void* d_ws, size_t ws_size,
                              hipStream_t stream)
{
    const float* f    = (const float*)d_in[0];
    const float* c1w  = (const float*)d_in[2];
    const float* c1b  = (const float*)d_in[3];
    const float* regw = (const float*)d_in[4];
    const float* regb = (const float*)d_in[5];
    const float* clsw = (const float*)d_in[6];
    const float* clsb = (const float*)d_in[7];
    const float* lmw  = (const float*)d_in[8];
    const float* lmb  = (const float*)d_in[9];

    float* out      = (float*)d_out;
    float* rois     = out;
    float* lm_out   = out + 24;
    float* anch_out = out + 24 + (size_t)NPOS*54;

    char* ws = (char*)d_ws;

    if (ws_size >= 124111104ull) {
        // ---- MFMA path layout ----
        unsigned long long* slot = (unsigned long long*)ws;
        float* wbox   = (float*)(ws + 16);
        float* wT     = (float*)(ws + 256);                         // 202,752
        unsigned short* fph = (unsigned short*)(ws + 203008);       // 26,873,856
        unsigned short* fpl = (unsigned short*)(ws + 27076864);     // 26,873,856
        unsigned short* wth = (unsigned short*)(ws + 53950720);     //  4,718,592
        unsigned short* wtl = (unsigned short*)(ws + 58669312);     //  4,718,592
        float* x      = (float*)(ws + 63387904);                    // 52,428,800
        float* deltas = (float*)(ws + 115816704);                   //  3,686,400
        float* boxes  = (float*)(ws + 119503104);                   //  3,686,400
        float* s_arr  = (float*)(ws + 123189504);                   //    921,600

        wprep_kernel<<<(99*512 + 255)/256, 256, 0, stream>>>(regw, clsw, lmw, wT);
        fprep_kernel<<<13122, 256, 0, stream>>>(f, fph, fpl);
        wprep2_kernel<<<dim3(144, 16), 256, 0, stream>>>(c1w, wth, wtl);
        conv1_mfma_kernel<<<dim3(4, 200), 256, 0, stream>>>(fph, fpl, wth, wtl, c1b, x);
        heads_kernel<<<NPOS/16, 256, 0, stream>>>(x, wT, regb, clsb, lmb,
                                                  lm_out, deltas, s_arr);
        decode_kernel<<<NANCH/256, 256, 0, stream>>>(deltas, s_arr, boxes,
                                                     anch_out, slot);
        for (int k = 0; k < 6; ++k) {
            nms_iter_kernel<<<NANCH/256, 256, 0, stream>>>(boxes, s_arr, wbox, slot, k);
            nms_pick_kernel<<<1, 64, 0, stream>>>(boxes, wbox, slot, rois, k);
        }
    } else {
        // ---- fallback fp32 path (round-1 layout) ----
        unsigned long long* slot = (unsigned long long*)ws;
        float* wbox   = (float*)(ws + 16);
        float* wT     = (float*)(ws + 256);
        float* boxes  = (float*)(ws + 256 + 202752);
        float* deltas = (float*)(ws + 256 + 202752 + 3686400);
        float* s_arr  = (float*)(ws + 256 + 202752 + 2*3686400);
        float* x      = (float*)(ws + 256 + 202752 + 2*3686400 + 921600);

        wprep_kernel<<<(99*512 + 255)/256, 256, 0, stream>>>(regw, clsw, lmw, wT);
        conv1_kernel<<<dim3(8, 400), 256, 0, stream>>>(f, c1w, c1b, x);
        heads_kernel<<<NPOS/16, 256, 0, stream>>>(x, wT, regb, clsb, lmb,
                                                  lm_out, deltas, s_arr);
        decode_kernel<<<NANCH/256, 256, 0, stream>>>(deltas, s_arr, boxes,
                                                     anch_out, slot);
        for (int k = 0; k < 6; ++k) {
            nms_iter_kernel<<<NANCH/256, 256, 0, stream>>>(boxes, s_arr, wbox, slot, k);
            nms_pick_kernel<<<1, 64, 0, stream>>>(boxes, wbox, slot, rois, k);
        }
    }
}

// Round 3
// 706.709 us; speedup vs baseline: 4.3585x; 1.4782x over previous
//
#include <hip/hip_runtime.h>
#include <math.h>

#define FH 160
#define FW 160
#define NPOS (FH*FW)        // 25600
#define NANCH (NPOS*9)      // 230400
#define IMG 2560.0f
#define STRIDE 16.0f

typedef __attribute__((ext_vector_type(8))) short short8;
typedef __attribute__((ext_vector_type(4))) float f32x4;

__device__ __forceinline__ unsigned short bf16_rne(float v) {
    unsigned u = __float_as_uint(v);
    return (unsigned short)((u + 0x7FFFu + ((u >> 16) & 1u)) >> 16);
}
__device__ __forceinline__ float bf16_to_f(unsigned short b) {
    return __uint_as_float(((unsigned)b) << 16);
}
__device__ __forceinline__ void g2l16(void* lds, const void* g) {
    __builtin_amdgcn_global_load_lds(
        (const __attribute__((address_space(1))) void*)g,
        (__attribute__((address_space(3))) void*)lds, 16, 0, 0);
}

// ---------------------------------------------------------------------------
// fprep: pad features to [162][162][512], fp32 -> bf16 (hi only; the Al*Bh
// correction term is dropped — 2^-9 relative, safe vs thresholds/argmax gap).
// ---------------------------------------------------------------------------
__global__ __launch_bounds__(256) void fprep_kernel(
    const float* __restrict__ f, unsigned short* __restrict__ fph)
{
    int idx = blockIdx.x*256 + threadIdx.x;   // 162*162*128
    int c4 = (idx & 127) << 2;
    int rest = idx >> 7;
    int x = rest % 162, y = rest / 162;
    float4 v = make_float4(0.f, 0.f, 0.f, 0.f);
    if (y > 0 && y < 161 && x > 0 && x < 161)
        v = *(const float4*)(f + ((size_t)((y-1)*FW + (x-1)) << 9) + c4);
    ushort4 h;
    h.x = bf16_rne(v.x); h.y = bf16_rne(v.y);
    h.z = bf16_rne(v.z); h.w = bf16_rne(v.w);
    *(ushort4*)(fph + ((size_t)(y*162 + x) << 9) + c4) = h;
}

// ---------------------------------------------------------------------------
// wprep2: transpose conv1 weights [4608 k][512 oc] -> [512 oc][4608 k],
// split to bf16 hi/lo (weight-lo term kept: Ah*Bh + Ah*Bl).
// ---------------------------------------------------------------------------
__global__ __launch_bounds__(256) void wprep2_kernel(
    const float* __restrict__ w, unsigned short* __restrict__ wth,
    unsigned short* __restrict__ wtl)
{
    __shared__ float tile[32][33];
    int k0 = blockIdx.x*32, oc0 = blockIdx.y*32;
    int t = threadIdx.x;
    int c = t & 31, r8 = t >> 5;
#pragma unroll
    for (int i = 0; i < 4; ++i) {
        int r = r8 + i*8;
        tile[c][r] = w[(size_t)(k0 + r)*512 + oc0 + c];
    }
    __syncthreads();
#pragma unroll
    for (int i = 0; i < 4; ++i) {
        int orow = r8 + i*8, kcol = c;
        float v = tile[orow][kcol];
        unsigned short hi = bf16_rne(v);
        unsigned short lo = bf16_rne(v - bf16_to_f(hi));
        size_t o = (size_t)(oc0 + orow)*4608 + k0 + kcol;
        wth[o] = hi; wtl[o] = lo;
    }
}

// ---------------------------------------------------------------------------
// whprep: head weights -> padded [128 u][512 c] bf16 hi/lo.
// u<36: reg (u/4)*8+u%4 ; 36..44: cls ; 45..98: lm ; 99..127: zero pad
// ---------------------------------------------------------------------------
__global__ __launch_bounds__(256) void whprep_kernel(
    const float* __restrict__ regw, const float* __restrict__ clsw,
    const float* __restrict__ lmw, unsigned short* __restrict__ whh,
    unsigned short* __restrict__ whl)
{
    int i = blockIdx.x*256 + threadIdx.x;   // 65536
    int u = i >> 9, c = i & 511;
    float v = 0.f;
    if (u < 36)      v = regw[c*72 + (u>>2)*8 + (u&3)];
    else if (u < 45) v = clsw[c*9 + (u-36)];
    else if (u < 99) v = lmw[c*54 + (u-45)];
    unsigned short h = bf16_rne(v);
    whh[i] = h; whl[i] = bf16_rne(v - bf16_to_f(h));
}

// ---------------------------------------------------------------------------
// conv1 via MFMA, 2-term (Ah*Bh + Ah*Bl), BK=64, XOR-swizzled LDS.
// Tile BM=128 (4y x 32x) BN=128, 256 thr (2x2 waves), 72 K-chunks.
// Swizzle: lds[row][kphys] holds global k = kphys ^ ((row&3)<<4); applied by
// permuting the GLOBAL address per lane (global_load_lds lds addr is forced
// linear base+lane*16). Frag reads then hit all 32 banks.
// XCD stripe: bid&7 -> one oc-panel per XCD pair (B-panel 2.36MB < 4MB L2).
// ---------------------------------------------------------------------------
__global__ __launch_bounds__(256) void conv1_mfma_kernel(
    const unsigned short* __restrict__ fph,
    const unsigned short* __restrict__ wth, const unsigned short* __restrict__ wtl,
    const float* __restrict__ bias, unsigned short* __restrict__ xh)
{
    __shared__ unsigned short As[128*64];
    __shared__ unsigned short Bh[128*64];
    __shared__ unsigned short Bl[128*64];
    const int tid  = threadIdx.x;
    const int lane = tid & 63;
    const int wi   = (tid >> 7) & 1;
    const int wj   = (tid >> 6) & 1;
    const int bid  = blockIdx.x;
    const int xcd  = bid & 7, sl = bid >> 3;
    const int oc0  = (xcd & 3) * 128;
    const int pt   = (xcd >> 2) * 100 + sl;
    const int ty = pt / 5, tx = pt - ty*5;
    const int y0 = ty*4, x0 = tx*32;

    const int srow0 = tid >> 3;                         // 0..31
    const int kswz  = ((tid & 7) << 3) ^ ((srow0 & 3) << 4);
    unsigned short* dA = As + tid*8;
    unsigned short* dBh = Bh + tid*8;
    unsigned short* dBl = Bl + tid*8;

    const int quad = lane >> 4, fr = lane & 15;
    f32x4 acc[4][4] = {};

    const size_t bOfs = (size_t)(oc0 + srow0)*4608 + kswz;

    for (int tap = 0; tap < 9; ++tap) {
        const int ky = tap/3, kx = tap - (tap/3)*3;
        const size_t aOfs = ((size_t)((y0 + ky)*162 + (x0 + srow0 + kx)) << 9) + kswz;
        for (int icb = 0; icb < 512; icb += 64) {
            const unsigned short* gA = fph + aOfs + icb;
            const unsigned short* gB0 = wth + bOfs + tap*512 + icb;
            const unsigned short* gB1 = wtl + bOfs + tap*512 + icb;
#pragma unroll
            for (int p = 0; p < 4; ++p) {
                g2l16(dA  + p*2048, gA  + (size_t)p*162*512);
                g2l16(dBh + p*2048, gB0 + (size_t)p*32*4608);
                g2l16(dBl + p*2048, gB1 + (size_t)p*32*4608);
            }
            __syncthreads();
#pragma unroll
            for (int kk = 0; kk < 2; ++kk) {
                const int sa = (kk*32 + quad*8) ^ ((fr & 3) << 4);
                short8 a[4], bhv[4], blv[4];
#pragma unroll
                for (int b = 0; b < 4; ++b) {
                    a[b]   = *(const short8*)(As + (wi*64 + b*16 + fr)*64 + sa);
                    bhv[b] = *(const short8*)(Bh + (wj*64 + b*16 + fr)*64 + sa);
                    blv[b] = *(const short8*)(Bl + (wj*64 + b*16 + fr)*64 + sa);
                }
#pragma unroll
                for (int i = 0; i < 4; ++i)
#pragma unroll
                    for (int j = 0; j < 4; ++j) {
                        acc[i][j] = __builtin_amdgcn_mfma_f32_16x16x32_bf16(a[i], bhv[j], acc[i][j], 0, 0, 0);
                        acc[i][j] = __builtin_amdgcn_mfma_f32_16x16x32_bf16(a[i], blv[j], acc[i][j], 0, 0, 0);
                    }
            }
            __syncthreads();
        }
    }

    // epilogue: C/D col=lane&15 (oc), row=(lane>>4)*4+reg (pos); ReLU -> bf16
#pragma unroll
    for (int i = 0; i < 4; ++i) {
        int prow = wi*64 + i*16 + quad*4;
#pragma unroll
        for (int r = 0; r < 4; ++r) {
            int pi = prow + r;
            int p = (y0 + (pi >> 5))*FW + x0 + (pi & 31);
#pragma unroll
            for (int j = 0; j < 4; ++j) {
                int col = oc0 + wj*64 + j*16 + fr;
                float v = acc[i][j][r] + bias[col];
                xh[(size_t)p*512 + col] = bf16_rne(v > 0.f ? v : 0.f);
            }
        }
    }
}

// ---------------------------------------------------------------------------
// heads via MFMA: GEMM M=25600, N=128(99 used), K=512, 2-term (Xh*Wh + Xh*Wl).
// Same tile/swizzle machinery, 8 K-chunks, grid 200.
// ---------------------------------------------------------------------------
__global__ __launch_bounds__(256) void heads_mfma_kernel(
    const unsigned short* __restrict__ xh,
    const unsigned short* __restrict__ whh, const unsigned short* __restrict__ whl,
    const float* __restrict__ regb, const float* __restrict__ clsb,
    const float* __restrict__ lmb,
    float* __restrict__ lm_out, float* __restrict__ deltas,
    float* __restrict__ s_arr)
{
    __shared__ unsigned short As[128*64];
    __shared__ unsigned short Bh[128*64];
    __shared__ unsigned short Bl[128*64];
    const int tid  = threadIdx.x;
    const int lane = tid & 63;
    const int wi   = (tid >> 7) & 1;
    const int wj   = (tid >> 6) & 1;
    const int p0   = blockIdx.x * 128;

    const int srow0 = tid >> 3;
    const int kswz  = ((tid & 7) << 3) ^ ((srow0 & 3) << 4);
    unsigned short* dA = As + tid*8;
    unsigned short* dBh = Bh + tid*8;
    unsigned short* dBl = Bl + tid*8;

    const int quad = lane >> 4, fr = lane & 15;
    f32x4 acc[4][4] = {};

    const size_t aOfs = ((size_t)(p0 + srow0) << 9) + kswz;
    const size_t bOfs = ((size_t)srow0 << 9) + kswz;

    for (int icb = 0; icb < 512; icb += 64) {
        const unsigned short* gA = xh + aOfs + icb;
        const unsigned short* gB0 = whh + bOfs + icb;
        const unsigned short* gB1 = whl + bOfs + icb;
#pragma unroll
        for (int p = 0; p < 4; ++p) {
            g2l16(dA  + p*2048, gA  + (size_t)p*32*512);
            g2l16(dBh + p*2048, gB0 + (size_t)p*32*512);
            g2l16(dBl + p*2048, gB1 + (size_t)p*32*512);
        }
        __syncthreads();
#pragma unroll
        for (int kk = 0; kk < 2; ++kk) {
            const int sa = (kk*32 + quad*8) ^ ((fr & 3) << 4);
            short8 a[4], bhv[4], blv[4];
#pragma unroll
            for (int b = 0; b < 4; ++b) {
                a[b]   = *(const short8*)(As + (wi*64 + b*16 + fr)*64 + sa);
                bhv[b] = *(const short8*)(Bh + (wj*64 + b*16 + fr)*64 + sa);
                blv[b] = *(const short8*)(Bl + (wj*64 + b*16 + fr)*64 + sa);
            }
#pragma unroll
            for (int i = 0; i < 4; ++i)
#pragma unroll
                for (int j = 0; j < 4; ++j) {
                    acc[i][j] = __builtin_amdgcn_mfma_f32_16x16x32_bf16(a[i], bhv[j], acc[i][j], 0, 0, 0);
                    acc[i][j] = __builtin_amdgcn_mfma_f32_16x16x32_bf16(a[i], blv[j], acc[i][j], 0, 0, 0);
                }
        }
        __syncthreads();
    }

#pragma unroll
    for (int i = 0; i < 4; ++i) {
        int prow = wi*64 + i*16 + quad*4;
#pragma unroll
        for (int r = 0; r < 4; ++r) {
            int p = p0 + prow + r;
#pragma unroll
            for (int j = 0; j < 4; ++j) {
                int u = wj*64 + j*16 + fr;
                float v = acc[i][j][r];
                if (u < 36) {
                    int aidx = u >> 2, rr = u & 3;
                    deltas[(size_t)(p*9 + aidx)*4 + rr] = v + regb[aidx*8 + rr];
                } else if (u < 45) {
                    float z = v + clsb[u-36];
                    s_arr[p*9 + (u-36)] = 1.f/(1.f + expf(-z));
                } else if (u < 99) {
                    lm_out[(size_t)p*54 + (u-45)] = v + lmb[u-45];
                }
            }
        }
    }
}

// ---------------------------------------------------------------------------
// decode: anchors -> d_out, boxes -> ws, mask invalid scores, init slot.
// ---------------------------------------------------------------------------
__global__ __launch_bounds__(256) void decode_kernel(
    const float* __restrict__ deltas, float* __restrict__ s_arr,
    float* __restrict__ boxes, float* __restrict__ anch_out,
    unsigned long long* __restrict__ slot)
{
    int n = blockIdx.x*256 + threadIdx.x;
    if (n == 0) *slot = 0ull;
    if (n >= NANCH) return;
    int p = n / 9, a = n - 9*p;
    int y = p / FW, x = p - FW*y;
    float cx = (x + 0.5f)*STRIDE, cy = (y + 0.5f)*STRIDE;
    const float rr[3] = {0.5f, 1.f, 2.f};
    const float ss[3] = {8.f, 16.f, 32.f};
    float r = rr[a/3], sv = ss[a - (a/3)*3];
    float h  = sqrtf(sv*sv/r)*STRIDE;
    float wv = h * r;
    float x1a = cx - wv*0.5f, y1a = cy - h*0.5f;
    float x2a = cx + wv*0.5f, y2a = cy + h*0.5f;
    float4 av = {x1a, y1a, x2a, y2a};
    *(float4*)(anch_out + (size_t)4*n) = av;
    bool valid = (x1a >= 0.f) && (y1a >= 0.f) && (x2a <= IMG) && (y2a <= IMG);

    float4 d = *(const float4*)(deltas + (size_t)4*n);
    float px = cx + wv*d.x, py = cy + h*d.y;
    float pw = wv*expf(d.z), ph = h*expf(d.w);
    float bx1 = px - pw*0.5f, by1 = py - ph*0.5f;
    float4 b;
    b.x = fminf(fmaxf(bx1, 0.f), IMG);
    b.y = fminf(fmaxf(by1, 0.f), IMG);
    b.z = fminf(fmaxf(bx1 + pw, 0.f), IMG);
    b.w = fminf(fmaxf(by1 + ph, 0.f), IMG);
    *(float4*)(boxes + (size_t)4*n) = b;
    if (!valid) s_arr[n] = -1.f;
}

// ---------------------------------------------------------------------------
__global__ __launch_bounds__(256) void nms_iter_kernel(
    const float* __restrict__ boxes, float* __restrict__ s_arr,
    const float* __restrict__ wbox, unsigned long long* __restrict__ slot,
    int k)
{
    int n = blockIdx.x*256 + threadIdx.x;
    float s = s_arr[n];
    if (k > 0) {
        float wx1 = wbox[0], wy1 = wbox[1], wx2 = wbox[2], wy2 = wbox[3];
        float4 b = *(const float4*)(boxes + (size_t)4*n);
        float ix = fminf(wx2, b.z) - fmaxf(wx1, b.x);
        float iy = fminf(wy2, b.w) - fmaxf(wy1, b.y);
        float inter = fmaxf(ix, 0.f)*fmaxf(iy, 0.f);
        float a1 = (wx2-wx1)*(wy2-wy1);
        float a2 = (b.z-b.x)*(b.w-b.y);
        float iou = inter/(a1 + a2 - inter + 1e-9f);
        if (iou > 0.5f) { s = -1.f; s_arr[n] = -1.f; }
    }
    unsigned int bu = __float_as_uint(s);
    unsigned int key = (bu & 0x80000000u) ? ~bu : (bu | 0x80000000u);
    unsigned long long packed =
        ((unsigned long long)key << 32) | (unsigned int)~(unsigned int)n;
#pragma unroll
    for (int off = 32; off > 0; off >>= 1) {
        unsigned long long o = __shfl_xor(packed, off, 64);
        packed = packed > o ? packed : o;
    }
    if ((threadIdx.x & 63) == 0) atomicMax(slot, packed);
}

__global__ void nms_pick_kernel(
    const float* __restrict__ boxes, float* __restrict__ wbox,
    unsigned long long* __restrict__ slot, float* __restrict__ rois, int k)
{
    if (threadIdx.x != 0) return;
    unsigned long long v = *slot;
    unsigned int n = ~(unsigned int)(v & 0xFFFFFFFFull);
    float4 b = *(const float4*)(boxes + (size_t)4*n);
    wbox[0] = b.x; wbox[1] = b.y; wbox[2] = b.z; wbox[3] = b.w;
    rois[k*4+0] = b.x; rois[k*4+1] = b.y; rois[k*4+2] = b.z; rois[k*4+3] = b.w;
    *slot = 0ull;
}

// ---------------------------------------------------------------------------
// fallback fp32 path kernels (unchanged, known-good)
// ---------------------------------------------------------------------------
__global__ __launch_bounds__(256) void conv1_kernel(
    const float* __restrict__ f, const float* __restrict__ w,
    const float* __restrict__ bias, float* __restrict__ xout)
{
    __shared__ float As[32][66];
    __shared__ float Bs[32][66];
    const int tid = threadIdx.x;
    const int nt = blockIdx.x;
    const int mt = blockIdx.y;
    const int p0 = mt*64, oc0 = nt*64;
    const int tm = tid & 15, tn = tid >> 4;
    const int kA = tid & 31, mA = tid >> 5;
    const int nB = tid & 63, kB = tid >> 6;
    int yv[8], xv[8];
#pragma unroll
    for (int it = 0; it < 8; ++it) {
        int p = p0 + mA + it*8;
        yv[it] = p / FW;
        xv[it] = p - yv[it]*FW;
    }
    float acc[4][4] = {};
    for (int tap = 0; tap < 9; ++tap) {
        const int ky = tap/3 - 1, kx = tap%3 - 1;
        for (int icb = 0; icb < 512; icb += 32) {
#pragma unroll
            for (int it = 0; it < 8; ++it) {
                int yy = yv[it] + ky, xx = xv[it] + kx;
                float v = 0.f;
                if ((unsigned)yy < (unsigned)FH && (unsigned)xx < (unsigned)FW)
                    v = f[(((yy*FW)+xx)<<9) + icb + kA];
                As[kA][mA + it*8] = v;
            }
            const float* wp = w + ((size_t)(tap*512 + icb + kB))*512 + oc0 + nB;
#pragma unroll
            for (int it = 0; it < 8; ++it)
                Bs[kB + it*4][nB] = wp[(size_t)it*4*512];
            __syncthreads();
#pragma unroll 8
            for (int kk = 0; kk < 32; ++kk) {
                float a0 = As[kk][4*tm+0], a1 = As[kk][4*tm+1],
                      a2 = As[kk][4*tm+2], a3 = As[kk][4*tm+3];
                float b0 = Bs[kk][4*tn+0], b1 = Bs[kk][4*tn+1],
                      b2 = Bs[kk][4*tn+2], b3 = Bs[kk][4*tn+3];
                acc[0][0] += a0*b0; acc[0][1] += a0*b1; acc[0][2] += a0*b2; acc[0][3] += a0*b3;
                acc[1][0] += a1*b0; acc[1][1] += a1*b1; acc[1][2] += a1*b2; acc[1][3] += a1*b3;
                acc[2][0] += a2*b0; acc[2][1] += a2*b1; acc[2][2] += a2*b2; acc[2][3] += a2*b3;
                acc[3][0] += a3*b0; acc[3][1] += a3*b1; acc[3][2] += a3*b2; acc[3][3] += a3*b3;
            }
            __syncthreads();
        }
    }
#pragma unroll
    for (int i = 0; i < 4; ++i) {
        int p = p0 + 4*tm + i;
        float4 o;
        float* op = &o.x;
#pragma unroll
        for (int j = 0; j < 4; ++j) {
            float v = acc[i][j] + bias[oc0 + 4*tn + j];
            op[j] = v > 0.f ? v : 0.f;
        }
        *(float4*)(xout + (size_t)p*512 + oc0 + 4*tn) = o;
    }
}

__global__ __launch_bounds__(256) void wprep_kernel(
    const float* __restrict__ regw, const float* __restrict__ clsw,
    const float* __restrict__ lmw, float* __restrict__ wT)
{
    int i = blockIdx.x*256 + threadIdx.x;
    if (i >= 99*512) return;
    int u = i >> 9, c = i & 511;
    float v;
    if (u < 36)      v = regw[c*72 + (u>>2)*8 + (u&3)];
    else if (u < 45) v = clsw[c*9 + (u-36)];
    else             v = lmw[c*54 + (u-45)];
    wT[i] = v;
}

__global__ __launch_bounds__(256) void heads_kernel(
    const float* __restrict__ x, const float* __restrict__ wT,
    const float* __restrict__ regb, const float* __restrict__ clsb,
    const float* __restrict__ lmb,
    float* __restrict__ lm_out, float* __restrict__ deltas,
    float* __restrict__ s_arr)
{
    __shared__ float xs[16*516];
    const int p0 = blockIdx.x * 16;
    const float4* src = (const float4*)(x + (size_t)p0*512);
    for (int i = threadIdx.x; i < 16*128; i += 256) {
        int row = i >> 7, c4 = i & 127;
        *(float4*)(xs + row*516 + c4*4) = src[row*128 + c4];
    }
    __syncthreads();
    for (int oi = threadIdx.x; oi < 99*16; oi += 256) {
        int ps = oi & 15, u = oi >> 4;
        const float4* wv = (const float4*)(wT + (u << 9));
        const float4* xv = (const float4*)(xs + ps*516);
        float acc = 0.f;
#pragma unroll 4
        for (int c = 0; c < 128; ++c) {
            float4 a = xv[c], b = wv[c];
            acc += a.x*b.x + a.y*b.y + a.z*b.z + a.w*b.w;
        }
        int p = p0 + ps;
        if (u < 36) {
            int aidx = u >> 2, r = u & 3;
            deltas[(size_t)(p*9 + aidx)*4 + r] = acc + regb[aidx*8 + r];
        } else if (u < 45) {
            float z = acc + clsb[u-36];
            s_arr[p*9 + (u-36)] = 1.f/(1.f + expf(-z));
        } else {
            lm_out[(size_t)p*54 + (u-45)] = acc + lmb[u-45];
        }
    }
}

// ---------------------------------------------------------------------------
extern "C" void kernel_launch(void* const* d_in, const int* in_sizes, int n_in,
                              void* d_out, int out_size, void* d_ws, size_t ws_size,
                              hipStream_t stream)
{
    const float* f    = (const float*)d_in[0];
    const float* c1w  = (const float*)d_in[2];
    const float* c1b  = (const float*)d_in[3];
    const float* regw = (const float*)d_in[4];
    const float* regb = (const float*)d_in[5];
    const float* clsw = (const float*)d_in[6];
    const float* clsb = (const float*)d_in[7];
    const float* lmw  = (const float*)d_in[8];
    const float* lmb  = (const float*)d_in[9];

    float* out      = (float*)d_out;
    float* rois     = out;
    float* lm_out   = out + 24;
    float* anch_out = out + 24 + (size_t)NPOS*54;

    char* ws = (char*)d_ws;

    if (ws_size >= 71082240ull) {
        unsigned long long* slot = (unsigned long long*)ws;
        float* wbox = (float*)(ws + 16);
        unsigned short* whh = (unsigned short*)(ws + 256);        //   131,072
        unsigned short* whl = (unsigned short*)(ws + 131328);     //   131,072
        unsigned short* fph = (unsigned short*)(ws + 262400);     // 26,873,856
        unsigned short* wth = (unsigned short*)(ws + 27136256);   //  4,718,592
        unsigned short* wtl = (unsigned short*)(ws + 31854848);   //  4,718,592
        unsigned short* xhh = (unsigned short*)(ws + 36573440);   // 26,214,400
        float* deltas = (float*)(ws + 62787840);                  //  3,686,400
        float* boxes  = (float*)(ws + 66474240);                  //  3,686,400
        float* s_arr  = (float*)(ws + 70160640);                  //    921,600

        whprep_kernel<<<256, 256, 0, stream>>>(regw, clsw, lmw, whh, whl);
        fprep_kernel<<<13122, 256, 0, stream>>>(f, fph);
        wprep2_kernel<<<dim3(144, 16), 256, 0, stream>>>(c1w, wth, wtl);
        conv1_mfma_kernel<<<800, 256, 0, stream>>>(fph, wth, wtl, c1b, xhh);
        heads_mfma_kernel<<<200, 256, 0, stream>>>(xhh, whh, whl, regb, clsb, lmb,
                                                   lm_out, deltas, s_arr);
        decode_kernel<<<NANCH/256, 256, 0, stream>>>(deltas, s_arr, boxes,
                                                     anch_out, slot);
        for (int k = 0; k < 6; ++k) {
            nms_iter_kernel<<<NANCH/256, 256, 0, stream>>>(boxes, s_arr, wbox, slot, k);
            nms_pick_kernel<<<1, 64, 0, stream>>>(boxes, wbox, slot, rois, k);
        }
    } else {
        unsigned long long* slot = (unsigned long long*)ws;
        float* wbox   = (float*)(ws + 16);
        float* wT     = (float*)(ws + 256);
        float* boxes  = (float*)(ws + 256 + 202752);
        float* deltas = (float*)(ws + 256 + 202752 + 3686400);
        float* s_arr  = (float*)(ws + 256 + 202752 + 2*3686400);
        float* x      = (float*)(ws + 256 + 202752 + 2*3686400 + 921600);

        wprep_kernel<<<(99*512 + 255)/256, 256, 0, stream>>>(regw, clsw, lmw, wT);
        conv1_kernel<<<dim3(8, 400), 256, 0, stream>>>(f, c1w, c1b, x);
        heads_kernel<<<NPOS/16, 256, 0, stream>>>(x, wT, regb, clsb, lmb,
                                                  lm_out, deltas, s_arr);
        decode_kernel<<<NANCH/256, 256, 0, stream>>>(deltas, s_arr, boxes,
                                                     anch_out, slot);
        for (int k = 0; k < 6; ++k) {
            nms_iter_kernel<<<NANCH/256, 256, 0, stream>>>(boxes, s_arr, wbox, slot, k);
            nms_pick_kernel<<<1, 64, 0, stream>>>(boxes, wbox, slot, rois, k);
        }
    }
}